// Round 1
// baseline (242.196 us; speedup 1.0000x reference)
//
#include <hip/hip_runtime.h>

// Problem constants (fixed by the reference)
#define S_LEN 2048
#define B_DIM 16
#define D_DIM 256
#define K_DIM 2048
#define E_NUM 1048576

typedef __attribute__((ext_vector_type(4))) float f32x4;
typedef __attribute__((ext_vector_type(8))) short s16x8;
typedef __attribute__((ext_vector_type(4))) unsigned short u16x4;
typedef __attribute__((ext_vector_type(8))) unsigned short u16x8;

__device__ __forceinline__ unsigned short f2bf(float f) {
    unsigned int u = __float_as_uint(f);
    u += 0x7fffu + ((u >> 16) & 1u);   // round-to-nearest-even
    return (unsigned short)(u >> 16);
}

// K0: convert W (K,D) fp32 -> bf16 once (halves per-block streaming bytes)
__global__ void wcvt_kernel(const float* __restrict__ W, unsigned short* __restrict__ Wbf) {
    int t = blockIdx.x * 256 + threadIdx.x;          // 131072 threads, 1 float4 each
    f32x4 v = ((const f32x4*)W)[t];
    u16x4 u;
    u.x = f2bf(v.x); u.y = f2bf(v.y); u.z = f2bf(v.z); u.w = f2bf(v.w);
    ((u16x4*)Wbf)[t] = u;
}

// K2: build dedup bitmask: one uint64 per (b,k,s-block-of-64)
__global__ void maskbuild_kernel(const int* __restrict__ eb, const int* __restrict__ ij,
                                 unsigned long long* __restrict__ mw) {
    int e = blockIdx.x * 256 + threadIdx.x;
    int b = eb[e];
    int i = ij[2 * e];
    int j = ij[2 * e + 1];
    size_t w = ((size_t)(b * K_DIM + i)) * 32 + (j >> 6);
    atomicOr(&mw[w], 1ull << (j & 63));
}

// K3: fused GEMM (bf16 MFMA) + per-(k, s-block) softmax partials + edge x-scatter.
// Block = (b, 64 consecutive s). M-chunk resident in LDS; streams all K in tiles of 64.
__launch_bounds__(256, 2)
__global__ void gemm_softmax_kernel(const float* __restrict__ M,
                                    const unsigned short* __restrict__ Wbf,
                                    const unsigned long long* __restrict__ mw,
                                    float* __restrict__ out,
                                    float* __restrict__ pm, float* __restrict__ pz,
                                    float* __restrict__ pze) {
    __shared__ unsigned short Msh[64 * 264];   // 64 s x 256 d bf16, pitch 264
    __shared__ unsigned short Wsh[64 * 264];   // 64 k x 256 d bf16, pitch 264

    const int tid  = threadIdx.x;
    const int b    = blockIdx.x >> 5;
    const int sblk = blockIdx.x & 31;
    const int s0   = sblk * 64;
    const int lane = tid & 63;
    const int w    = tid >> 6;        // wave 0..3
    const int r    = lane & 15;
    const int g    = lane >> 4;       // 0..3

    // Stage M chunk: 64 rows x 256 d, fp32 -> bf16
    #pragma unroll
    for (int i = 0; i < 16; ++i) {
        int f4  = i * 256 + tid;
        int row = f4 >> 6;
        int c4  = f4 & 63;
        f32x4 v = *(const f32x4*)&M[((size_t)(s0 + row) * B_DIM + b) * D_DIM + c4 * 4];
        u16x4 u;
        u.x = f2bf(v.x); u.y = f2bf(v.y); u.z = f2bf(v.z); u.w = f2bf(v.w);
        *(u16x4*)&Msh[row * 264 + c4 * 4] = u;
    }

    for (int kt = 0; kt < 32; ++kt) {
        __syncthreads();              // previous iter done reading Wsh
        const int k0 = kt * 64;
        // Stage W tile: 64 k-rows x 256 d (bf16 in global already)
        #pragma unroll
        for (int i = 0; i < 8; ++i) {
            int u8  = i * 256 + tid;
            int row = u8 >> 5;
            int c8  = u8 & 31;
            u16x8 v = *(const u16x8*)&Wbf[(size_t)(k0 + row) * D_DIM + c8 * 8];
            *(u16x8*)&Wsh[row * 264 + c8 * 8] = v;
        }
        __syncthreads();

        // Wave w owns k-cols [k0 + w*16, +16). Output tile: 64 s x 16 k.
        f32x4 acc[4];
        #pragma unroll
        for (int st = 0; st < 4; ++st) acc[st] = (f32x4){0.f, 0.f, 0.f, 0.f};

        #pragma unroll
        for (int d = 0; d < 8; ++d) {
            int doff = d * 32 + g * 8;
            s16x8 bf = *(const s16x8*)&Wsh[(w * 16 + r) * 264 + doff];
            #pragma unroll
            for (int st = 0; st < 4; ++st) {
                s16x8 a = *(const s16x8*)&Msh[(st * 16 + r) * 264 + doff];
                acc[st] = __builtin_amdgcn_mfma_f32_16x16x32_bf16(a, bf, acc[st], 0, 0, 0);
            }
        }

        // Lane's k column; C layout: col = lane&15, row = g*4 + reg (+ st*16)
        const int kc = k0 + w * 16 + r;
        const unsigned long long w64 = mw[(size_t)(b * K_DIM + kc) * 32 + sblk];

        // Column max over the 64 s in this block
        float mx = acc[0][0];
        #pragma unroll
        for (int st = 0; st < 4; ++st)
            #pragma unroll
            for (int rr = 0; rr < 4; ++rr) mx = fmaxf(mx, acc[st][rr]);
        mx = fmaxf(mx, __shfl_xor(mx, 16));
        mx = fmaxf(mx, __shfl_xor(mx, 32));

        float zs = 0.f, ze = 0.f;
        const size_t obase = (size_t)(b * K_DIM + kc) * S_LEN + s0;
        #pragma unroll
        for (int st = 0; st < 4; ++st) {
            #pragma unroll
            for (int rr = 0; rr < 4; ++rr) {
                float v = acc[st][rr];
                float e = __expf(v - mx);
                zs += e;
                int pos = st * 16 + g * 4 + rr;   // s_local
                if ((w64 >> pos) & 1ull) {
                    ze += e;
                    out[obase + pos] = v;          // raw scale at edge position
                }
            }
        }
        zs += __shfl_xor(zs, 16); zs += __shfl_xor(zs, 32);
        ze += __shfl_xor(ze, 16); ze += __shfl_xor(ze, 32);

        if (lane < 16) {
            size_t pidx = (size_t)(b * 32 + sblk) * K_DIM + kc;
            pm[pidx]  = mx;
            pz[pidx]  = zs;
            pze[pidx] = ze;
        }
    }
}

// K4: combine the 32 s-block partials per (b,k) row -> final max and 1/denom
__global__ void combine_kernel(const float* __restrict__ pm, const float* __restrict__ pz,
                               const float* __restrict__ pze,
                               float* __restrict__ mfin, float* __restrict__ rd) {
    int t = blockIdx.x * 256 + threadIdx.x;   // 32768 rows
    int b = t >> 11;
    int k = t & 2047;
    float m = -3.4e38f;
    for (int p = 0; p < 32; ++p)
        m = fmaxf(m, pm[(size_t)(b * 32 + p) * K_DIM + k]);
    float Z = 0.f, Ze = 0.f;
    for (int p = 0; p < 32; ++p) {
        size_t idx = (size_t)(b * 32 + p) * K_DIM + k;
        float sc = __expf(pm[idx] - m);
        Z  += pz[idx]  * sc;
        Ze += pze[idx] * sc;
    }
    float denom = 1e-10f * (Z - Ze) + Ze;
    mfin[t] = m;
    rd[t]   = 1.0f / denom;
}

// K5a: per-edge score into a temp array (read-before-write safety for duplicate edges)
__global__ void edge_score_kernel(const int* __restrict__ eb, const int* __restrict__ ij,
                                  const float* __restrict__ out,
                                  const float* __restrict__ mfin, const float* __restrict__ rd,
                                  float* __restrict__ esc) {
    int e = blockIdx.x * 256 + threadIdx.x;
    int b = eb[e];
    int i = ij[2 * e];
    int j = ij[2 * e + 1];
    int row = b * K_DIM + i;
    float x = out[(size_t)row * S_LEN + j];
    esc[e] = __expf(x - mfin[row]) * rd[row];
}

// K5b: scatter scores (duplicates write identical values)
__global__ void edge_write_kernel(const int* __restrict__ eb, const int* __restrict__ ij,
                                  const float* __restrict__ esc, float* __restrict__ out) {
    int e = blockIdx.x * 256 + threadIdx.x;
    out[(size_t)(eb[e] * K_DIM + ij[2 * e]) * S_LEN + ij[2 * e + 1]] = esc[e];
}

extern "C" void kernel_launch(void* const* d_in, const int* in_sizes, int n_in,
                              void* d_out, int out_size, void* d_ws, size_t ws_size,
                              hipStream_t stream) {
    (void)in_sizes; (void)n_in; (void)ws_size;
    const float* M  = (const float*)d_in[0];
    const float* W  = (const float*)d_in[1];
    // d_in[2] = lengths: unused by the reference computation
    const int* eb   = (const int*)d_in[3];
    const int* ij   = (const int*)d_in[4];
    float* out      = (float*)d_out;
    char* ws        = (char*)d_ws;

    // Workspace layout (26,476,544 bytes total)
    unsigned long long* mw = (unsigned long long*)ws;            //  8,388,608
    float* pm   = (float*)(ws + 8388608);                        //  4,194,304
    float* pz   = (float*)(ws + 12582912);                       //  4,194,304
    float* pze  = (float*)(ws + 16777216);                       //  4,194,304
    float* mfin = (float*)(ws + 20971520);                       //    131,072
    float* rd   = (float*)(ws + 21102592);                       //    131,072
    float* esc  = (float*)(ws + 21233664);                       //  4,194,304
    unsigned short* Wbf = (unsigned short*)(ws + 25427968);      //  1,048,576

    hipMemsetAsync(d_out, 0, (size_t)out_size * sizeof(float), stream);
    hipMemsetAsync(mw, 0, 8388608, stream);

    wcvt_kernel<<<512, 256, 0, stream>>>(W, Wbf);
    maskbuild_kernel<<<E_NUM / 256, 256, 0, stream>>>(eb, ij, mw);
    gemm_softmax_kernel<<<512, 256, 0, stream>>>(M, Wbf, mw, out, pm, pz, pze);
    combine_kernel<<<128, 256, 0, stream>>>(pm, pz, pze, mfin, rd);
    edge_score_kernel<<<E_NUM / 256, 256, 0, stream>>>(eb, ij, out, mfin, rd, esc);
    edge_write_kernel<<<E_NUM / 256, 256, 0, stream>>>(eb, ij, esc, out);
}

// Round 2
// 202.712 us; speedup vs baseline: 1.1948x; 1.1948x over previous
//
#include <hip/hip_runtime.h>

// Problem constants (fixed by the reference)
#define S_LEN 2048
#define B_DIM 16
#define D_DIM 256
#define K_DIM 2048
#define E_NUM 1048576

typedef __attribute__((ext_vector_type(4))) float f32x4;
typedef __attribute__((ext_vector_type(8))) short s16x8;
typedef __attribute__((ext_vector_type(4))) unsigned short u16x4;
typedef __attribute__((ext_vector_type(8))) unsigned short u16x8;

__device__ __forceinline__ unsigned short f2bf(float f) {
    unsigned int u = __float_as_uint(f);
    u += 0x7fffu + ((u >> 16) & 1u);   // round-to-nearest-even
    return (unsigned short)(u >> 16);
}

// K0: convert W (K,D) fp32 -> bf16 once (halves per-block streaming bytes)
__global__ void wcvt_kernel(const float* __restrict__ W, unsigned short* __restrict__ Wbf) {
    int t = blockIdx.x * 256 + threadIdx.x;          // 131072 threads, 1 float4 each
    f32x4 v = ((const f32x4*)W)[t];
    u16x4 u;
    u.x = f2bf(v.x); u.y = f2bf(v.y); u.z = f2bf(v.z); u.w = f2bf(v.w);
    ((u16x4*)Wbf)[t] = u;
}

// K2: build dedup bitmask: one uint64 per (b,k,s-block-of-64)
__global__ void maskbuild_kernel(const int* __restrict__ eb, const int* __restrict__ ij,
                                 unsigned long long* __restrict__ mw) {
    int e = blockIdx.x * 256 + threadIdx.x;
    int b = eb[e];
    int i = ij[2 * e];
    int j = ij[2 * e + 1];
    size_t w = ((size_t)(b * K_DIM + i)) * 32 + (j >> 6);
    atomicOr(&mw[w], 1ull << (j & 63));
}

// K3: fused GEMM (bf16 MFMA) + per-(k, s-block) softmax partials + FULL tile write.
// Output tile write: edge ? raw_scale : 0  -> replaces the 268MB memset entirely.
// Block = (b, 64 consecutive s). M-chunk resident in LDS; streams all K in tiles of 64.
__launch_bounds__(256, 2)
__global__ void gemm_softmax_kernel(const float* __restrict__ M,
                                    const unsigned short* __restrict__ Wbf,
                                    const unsigned long long* __restrict__ mw,
                                    float* __restrict__ out,
                                    float* __restrict__ pm, float* __restrict__ pz,
                                    float* __restrict__ pze) {
    __shared__ unsigned short Msh[64 * 264];   // 64 s x 256 d bf16, pitch 264
    __shared__ unsigned short Wsh[64 * 264];   // 64 k x 256 d bf16, pitch 264

    const int tid  = threadIdx.x;
    const int b    = blockIdx.x >> 5;
    const int sblk = blockIdx.x & 31;
    const int s0   = sblk * 64;
    const int lane = tid & 63;
    const int w    = tid >> 6;        // wave 0..3
    const int r    = lane & 15;
    const int g    = lane >> 4;       // 0..3

    // Stage M chunk: 64 rows x 256 d, fp32 -> bf16
    #pragma unroll
    for (int i = 0; i < 16; ++i) {
        int f4  = i * 256 + tid;
        int row = f4 >> 6;
        int c4  = f4 & 63;
        f32x4 v = *(const f32x4*)&M[((size_t)(s0 + row) * B_DIM + b) * D_DIM + c4 * 4];
        u16x4 u;
        u.x = f2bf(v.x); u.y = f2bf(v.y); u.z = f2bf(v.z); u.w = f2bf(v.w);
        *(u16x4*)&Msh[row * 264 + c4 * 4] = u;
    }

    for (int kt = 0; kt < 32; ++kt) {
        __syncthreads();              // previous iter done reading Wsh
        const int k0 = kt * 64;
        // Stage W tile: 64 k-rows x 256 d (bf16 in global already)
        #pragma unroll
        for (int i = 0; i < 8; ++i) {
            int u8  = i * 256 + tid;
            int row = u8 >> 5;
            int c8  = u8 & 31;
            u16x8 v = *(const u16x8*)&Wbf[(size_t)(k0 + row) * D_DIM + c8 * 8];
            *(u16x8*)&Wsh[row * 264 + c8 * 8] = v;
        }
        __syncthreads();

        // Wave w owns k-cols [k0 + w*16, +16). Output tile: 64 s x 16 k.
        f32x4 acc[4];
        #pragma unroll
        for (int st = 0; st < 4; ++st) acc[st] = (f32x4){0.f, 0.f, 0.f, 0.f};

        #pragma unroll
        for (int d = 0; d < 8; ++d) {
            int doff = d * 32 + g * 8;
            s16x8 bf = *(const s16x8*)&Wsh[(w * 16 + r) * 264 + doff];
            #pragma unroll
            for (int st = 0; st < 4; ++st) {
                s16x8 a = *(const s16x8*)&Msh[(st * 16 + r) * 264 + doff];
                acc[st] = __builtin_amdgcn_mfma_f32_16x16x32_bf16(a, bf, acc[st], 0, 0, 0);
            }
        }

        // Lane's k column; C layout: col = lane&15, row = g*4 + reg (+ st*16)
        const int kc = k0 + w * 16 + r;
        const unsigned long long w64 = mw[(size_t)(b * K_DIM + kc) * 32 + sblk];

        // Column max over the 64 s in this block
        float mx = acc[0][0];
        #pragma unroll
        for (int st = 0; st < 4; ++st)
            #pragma unroll
            for (int rr = 0; rr < 4; ++rr) mx = fmaxf(mx, acc[st][rr]);
        mx = fmaxf(mx, __shfl_xor(mx, 16));
        mx = fmaxf(mx, __shfl_xor(mx, 32));

        float zs = 0.f, ze = 0.f;
        const size_t obase = (size_t)(b * K_DIM + kc) * S_LEN + s0;
        #pragma unroll
        for (int st = 0; st < 4; ++st) {
            f32x4 ov;
            #pragma unroll
            for (int rr = 0; rr < 4; ++rr) {
                float v = acc[st][rr];
                float e = __expf(v - mx);
                zs += e;
                int pos = st * 16 + g * 4 + rr;   // s_local
                bool edge = (w64 >> pos) & 1ull;
                ze += edge ? e : 0.f;
                ov[rr] = edge ? v : 0.f;           // raw scale at edges, 0 elsewhere
            }
            // 16B per lane; wave covers 16 k-rows x 64B contiguous s-segments
            *(f32x4*)&out[obase + st * 16 + g * 4] = ov;
        }
        zs += __shfl_xor(zs, 16); zs += __shfl_xor(zs, 32);
        ze += __shfl_xor(ze, 16); ze += __shfl_xor(ze, 32);

        if (lane < 16) {
            size_t pidx = (size_t)(b * 32 + sblk) * K_DIM + kc;
            pm[pidx]  = mx;
            pz[pidx]  = zs;
            pze[pidx] = ze;
        }
    }
}

// K4: combine the 32 s-block partials per (b,k) row -> final max and 1/denom
__global__ void combine_kernel(const float* __restrict__ pm, const float* __restrict__ pz,
                               const float* __restrict__ pze,
                               float* __restrict__ mfin, float* __restrict__ rd) {
    int t = blockIdx.x * 256 + threadIdx.x;   // 32768 rows
    int b = t >> 11;
    int k = t & 2047;
    float m = -3.4e38f;
    for (int p = 0; p < 32; ++p)
        m = fmaxf(m, pm[(size_t)(b * 32 + p) * K_DIM + k]);
    float Z = 0.f, Ze = 0.f;
    for (int p = 0; p < 32; ++p) {
        size_t idx = (size_t)(b * 32 + p) * K_DIM + k;
        float sc = __expf(pm[idx] - m);
        Z  += pz[idx]  * sc;
        Ze += pze[idx] * sc;
    }
    float denom = 1e-10f * (Z - Ze) + Ze;
    mfin[t] = m;
    rd[t]   = 1.0f / denom;
}

// K5a: per-edge score into a temp array (read-before-write safety for duplicate edges)
__global__ void edge_score_kernel(const int* __restrict__ eb, const int* __restrict__ ij,
                                  const float* __restrict__ out,
                                  const float* __restrict__ mfin, const float* __restrict__ rd,
                                  float* __restrict__ esc) {
    int e = blockIdx.x * 256 + threadIdx.x;
    int b = eb[e];
    int i = ij[2 * e];
    int j = ij[2 * e + 1];
    int row = b * K_DIM + i;
    float x = out[(size_t)row * S_LEN + j];
    esc[e] = __expf(x - mfin[row]) * rd[row];
}

// K5b: scatter scores (duplicates write identical values)
__global__ void edge_write_kernel(const int* __restrict__ eb, const int* __restrict__ ij,
                                  const float* __restrict__ esc, float* __restrict__ out) {
    int e = blockIdx.x * 256 + threadIdx.x;
    out[(size_t)(eb[e] * K_DIM + ij[2 * e]) * S_LEN + ij[2 * e + 1]] = esc[e];
}

extern "C" void kernel_launch(void* const* d_in, const int* in_sizes, int n_in,
                              void* d_out, int out_size, void* d_ws, size_t ws_size,
                              hipStream_t stream) {
    (void)in_sizes; (void)n_in; (void)ws_size; (void)out_size;
    const float* M  = (const float*)d_in[0];
    const float* W  = (const float*)d_in[1];
    // d_in[2] = lengths: unused by the reference computation
    const int* eb   = (const int*)d_in[3];
    const int* ij   = (const int*)d_in[4];
    float* out      = (float*)d_out;
    char* ws        = (char*)d_ws;

    // Workspace layout (26,476,544 bytes total)
    unsigned long long* mw = (unsigned long long*)ws;            //  8,388,608
    float* pm   = (float*)(ws + 8388608);                        //  4,194,304
    float* pz   = (float*)(ws + 12582912);                       //  4,194,304
    float* pze  = (float*)(ws + 16777216);                       //  4,194,304
    float* mfin = (float*)(ws + 20971520);                       //    131,072
    float* rd   = (float*)(ws + 21102592);                       //    131,072
    float* esc  = (float*)(ws + 21233664);                       //  4,194,304
    unsigned short* Wbf = (unsigned short*)(ws + 25427968);      //  1,048,576

    hipMemsetAsync(mw, 0, 8388608, stream);

    wcvt_kernel<<<512, 256, 0, stream>>>(W, Wbf);
    maskbuild_kernel<<<E_NUM / 256, 256, 0, stream>>>(eb, ij, mw);
    gemm_softmax_kernel<<<512, 256, 0, stream>>>(M, Wbf, mw, out, pm, pz, pze);
    combine_kernel<<<128, 256, 0, stream>>>(pm, pz, pze, mfin, rd);
    edge_score_kernel<<<E_NUM / 256, 256, 0, stream>>>(eb, ij, out, mfin, rd, esc);
    edge_write_kernel<<<E_NUM / 256, 256, 0, stream>>>(eb, ij, esc, out);
}

// Round 3
// 198.622 us; speedup vs baseline: 1.2194x; 1.0206x over previous
//
#include <hip/hip_runtime.h>

// Problem constants (fixed by the reference)
#define S_LEN 2048
#define B_DIM 16
#define D_DIM 256
#define K_DIM 2048
#define E_NUM 1048576

typedef __attribute__((ext_vector_type(4))) float f32x4;
typedef __attribute__((ext_vector_type(8))) short s16x8;
typedef __attribute__((ext_vector_type(4))) unsigned short u16x4;
typedef __attribute__((ext_vector_type(8))) unsigned short u16x8;

__device__ __forceinline__ unsigned short f2bf(float f) {
    unsigned int u = __float_as_uint(f);
    u += 0x7fffu + ((u >> 16) & 1u);   // round-to-nearest-even
    return (unsigned short)(u >> 16);
}

// K0: fused prep — zero the mask bitfield (runtime fillBufferAligned was 50 GB/s!)
// and convert W (K,D) fp32 -> bf16.
// blocks [0,2048): zero mw (16 B/thread). blocks [2048,2560): W convert.
__global__ void prep_kernel(const float* __restrict__ W, unsigned short* __restrict__ Wbf,
                            unsigned long long* __restrict__ mw) {
    int bid = blockIdx.x;
    if (bid < 2048) {
        int t = bid * 256 + threadIdx.x;           // 524288 threads x 16B = 8 MB
        ((f32x4*)mw)[t] = (f32x4){0.f, 0.f, 0.f, 0.f};
    } else {
        int t = (bid - 2048) * 256 + threadIdx.x;  // 131072 threads, 1 float4 each
        f32x4 v = ((const f32x4*)W)[t];
        u16x4 u;
        u.x = f2bf(v.x); u.y = f2bf(v.y); u.z = f2bf(v.z); u.w = f2bf(v.w);
        ((u16x4*)Wbf)[t] = u;
    }
}

// K2: build dedup bitmask: one uint64 per (b,k,s-block-of-64)
__global__ void maskbuild_kernel(const int* __restrict__ eb, const int* __restrict__ ij,
                                 unsigned long long* __restrict__ mw) {
    int e = blockIdx.x * 256 + threadIdx.x;
    int b = eb[e];
    int i = ij[2 * e];
    int j = ij[2 * e + 1];
    size_t w = ((size_t)(b * K_DIM + i)) * 32 + (j >> 6);
    atomicOr(&mw[w], 1ull << (j & 63));
}

// K3: fused GEMM (bf16 MFMA) + per-(k, s-block) softmax partials + FULL tile write.
// Output tile write: edge ? raw_scale : 0  -> replaces the 268MB memset entirely.
// Block = (b, 64 consecutive s). M-chunk resident in LDS; streams all K in tiles of 64.
__launch_bounds__(256, 2)
__global__ void gemm_softmax_kernel(const float* __restrict__ M,
                                    const unsigned short* __restrict__ Wbf,
                                    const unsigned long long* __restrict__ mw,
                                    float* __restrict__ out,
                                    float* __restrict__ pm, float* __restrict__ pz,
                                    float* __restrict__ pze) {
    __shared__ unsigned short Msh[64 * 264];   // 64 s x 256 d bf16, pitch 264
    __shared__ unsigned short Wsh[64 * 264];   // 64 k x 256 d bf16, pitch 264

    const int tid  = threadIdx.x;
    const int b    = blockIdx.x >> 5;
    const int sblk = blockIdx.x & 31;
    const int s0   = sblk * 64;
    const int lane = tid & 63;
    const int w    = tid >> 6;        // wave 0..3
    const int r    = lane & 15;
    const int g    = lane >> 4;       // 0..3

    // Stage M chunk: 64 rows x 256 d, fp32 -> bf16
    #pragma unroll
    for (int i = 0; i < 16; ++i) {
        int f4  = i * 256 + tid;
        int row = f4 >> 6;
        int c4  = f4 & 63;
        f32x4 v = *(const f32x4*)&M[((size_t)(s0 + row) * B_DIM + b) * D_DIM + c4 * 4];
        u16x4 u;
        u.x = f2bf(v.x); u.y = f2bf(v.y); u.z = f2bf(v.z); u.w = f2bf(v.w);
        *(u16x4*)&Msh[row * 264 + c4 * 4] = u;
    }

    for (int kt = 0; kt < 32; ++kt) {
        __syncthreads();              // previous iter done reading Wsh
        const int k0 = kt * 64;
        // Stage W tile: 64 k-rows x 256 d (bf16 in global already)
        #pragma unroll
        for (int i = 0; i < 8; ++i) {
            int u8  = i * 256 + tid;
            int row = u8 >> 5;
            int c8  = u8 & 31;
            u16x8 v = *(const u16x8*)&Wbf[(size_t)(k0 + row) * D_DIM + c8 * 8];
            *(u16x8*)&Wsh[row * 264 + c8 * 8] = v;
        }
        __syncthreads();

        // Wave w owns k-cols [k0 + w*16, +16). Output tile: 64 s x 16 k.
        f32x4 acc[4];
        #pragma unroll
        for (int st = 0; st < 4; ++st) acc[st] = (f32x4){0.f, 0.f, 0.f, 0.f};

        #pragma unroll
        for (int d = 0; d < 8; ++d) {
            int doff = d * 32 + g * 8;
            s16x8 bf = *(const s16x8*)&Wsh[(w * 16 + r) * 264 + doff];
            #pragma unroll
            for (int st = 0; st < 4; ++st) {
                s16x8 a = *(const s16x8*)&Msh[(st * 16 + r) * 264 + doff];
                acc[st] = __builtin_amdgcn_mfma_f32_16x16x32_bf16(a, bf, acc[st], 0, 0, 0);
            }
        }

        // Lane's k column; C layout: col = lane&15, row = g*4 + reg (+ st*16)
        const int kc = k0 + w * 16 + r;
        const unsigned long long w64 = mw[(size_t)(b * K_DIM + kc) * 32 + sblk];

        // Column max over the 64 s in this block
        float mx = acc[0][0];
        #pragma unroll
        for (int st = 0; st < 4; ++st)
            #pragma unroll
            for (int rr = 0; rr < 4; ++rr) mx = fmaxf(mx, acc[st][rr]);
        mx = fmaxf(mx, __shfl_xor(mx, 16));
        mx = fmaxf(mx, __shfl_xor(mx, 32));

        float zs = 0.f, ze = 0.f;
        const size_t obase = (size_t)(b * K_DIM + kc) * S_LEN + s0;
        #pragma unroll
        for (int st = 0; st < 4; ++st) {
            f32x4 ov;
            #pragma unroll
            for (int rr = 0; rr < 4; ++rr) {
                float v = acc[st][rr];
                float e = __expf(v - mx);
                zs += e;
                int pos = st * 16 + g * 4 + rr;   // s_local
                bool edge = (w64 >> pos) & 1ull;
                ze += edge ? e : 0.f;
                ov[rr] = edge ? v : 0.f;           // raw scale at edges, 0 elsewhere
            }
            // 16B per lane; wave covers 16 k-rows x 64B contiguous s-segments
            *(f32x4*)&out[obase + st * 16 + g * 4] = ov;
        }
        zs += __shfl_xor(zs, 16); zs += __shfl_xor(zs, 32);
        ze += __shfl_xor(ze, 16); ze += __shfl_xor(ze, 32);

        if (lane < 16) {
            size_t pidx = (size_t)(b * 32 + sblk) * K_DIM + kc;
            pm[pidx]  = mx;
            pz[pidx]  = zs;
            pze[pidx] = ze;
        }
    }
}

// K4: combine the 32 s-block partials per (b,k) row -> final max and 1/denom
__global__ void combine_kernel(const float* __restrict__ pm, const float* __restrict__ pz,
                               const float* __restrict__ pze,
                               float* __restrict__ mfin, float* __restrict__ rd) {
    int t = blockIdx.x * 256 + threadIdx.x;   // 32768 rows
    int b = t >> 11;
    int k = t & 2047;
    float m = -3.4e38f;
    for (int p = 0; p < 32; ++p)
        m = fmaxf(m, pm[(size_t)(b * 32 + p) * K_DIM + k]);
    float Z = 0.f, Ze = 0.f;
    for (int p = 0; p < 32; ++p) {
        size_t idx = (size_t)(b * 32 + p) * K_DIM + k;
        float sc = __expf(pm[idx] - m);
        Z  += pz[idx]  * sc;
        Ze += pze[idx] * sc;
    }
    float denom = 1e-10f * (Z - Ze) + Ze;
    mfin[t] = m;
    rd[t]   = 1.0f / denom;
}

// K5a: per-edge score into a temp array (read-before-write safety for duplicate edges)
__global__ void edge_score_kernel(const int* __restrict__ eb, const int* __restrict__ ij,
                                  const float* __restrict__ out,
                                  const float* __restrict__ mfin, const float* __restrict__ rd,
                                  float* __restrict__ esc) {
    int e = blockIdx.x * 256 + threadIdx.x;
    int b = eb[e];
    int i = ij[2 * e];
    int j = ij[2 * e + 1];
    int row = b * K_DIM + i;
    float x = out[(size_t)row * S_LEN + j];
    esc[e] = __expf(x - mfin[row]) * rd[row];
}

// K5b: scatter scores (duplicates write identical values)
__global__ void edge_write_kernel(const int* __restrict__ eb, const int* __restrict__ ij,
                                  const float* __restrict__ esc, float* __restrict__ out) {
    int e = blockIdx.x * 256 + threadIdx.x;
    out[(size_t)(eb[e] * K_DIM + ij[2 * e]) * S_LEN + ij[2 * e + 1]] = esc[e];
}

extern "C" void kernel_launch(void* const* d_in, const int* in_sizes, int n_in,
                              void* d_out, int out_size, void* d_ws, size_t ws_size,
                              hipStream_t stream) {
    (void)in_sizes; (void)n_in; (void)ws_size; (void)out_size;
    const float* M  = (const float*)d_in[0];
    const float* W  = (const float*)d_in[1];
    // d_in[2] = lengths: unused by the reference computation
    const int* eb   = (const int*)d_in[3];
    const int* ij   = (const int*)d_in[4];
    float* out      = (float*)d_out;
    char* ws        = (char*)d_ws;

    // Workspace layout (26,476,544 bytes total)
    unsigned long long* mw = (unsigned long long*)ws;            //  8,388,608
    float* pm   = (float*)(ws + 8388608);                        //  4,194,304
    float* pz   = (float*)(ws + 12582912);                       //  4,194,304
    float* pze  = (float*)(ws + 16777216);                       //  4,194,304
    float* mfin = (float*)(ws + 20971520);                       //    131,072
    float* rd   = (float*)(ws + 21102592);                       //    131,072
    float* esc  = (float*)(ws + 21233664);                       //  4,194,304
    unsigned short* Wbf = (unsigned short*)(ws + 25427968);      //  1,048,576

    prep_kernel<<<2560, 256, 0, stream>>>(W, Wbf, mw);
    maskbuild_kernel<<<E_NUM / 256, 256, 0, stream>>>(eb, ij, mw);
    gemm_softmax_kernel<<<512, 256, 0, stream>>>(M, Wbf, mw, out, pm, pz, pze);
    combine_kernel<<<128, 256, 0, stream>>>(pm, pz, pze, mfin, rd);
    edge_score_kernel<<<E_NUM / 256, 256, 0, stream>>>(eb, ij, out, mfin, rd, esc);
    edge_write_kernel<<<E_NUM / 256, 256, 0, stream>>>(eb, ij, esc, out);
}